// Round 10
// baseline (328.153 us; speedup 1.0000x reference)
//
#include <hip/hip_runtime.h>
#include <hip/hip_fp16.h>

#define DIM 64
#define BN_EPS 1e-5f
#define RSHIFT 8          // 256 nodes per range
#define RSIZE 256
#define EPB 8192          // edges per bin block

// ---------------- binhist: per-range edge counts via LDS histogram ----------------
__global__ __launch_bounds__(256) void k_binhist(const int* __restrict__ dst,
                                                 int* __restrict__ rangecnt,
                                                 int P, int E) {
    __shared__ int hist[512];
    for (int b = threadIdx.x; b < P; b += 256) hist[b] = 0;
    __syncthreads();
    const int base4 = blockIdx.x * (EPB / 4);
    for (int i = 0; i < EPB / 4 / 256; ++i) {
        int idx = base4 + i * 256 + threadIdx.x;
        int e0 = idx << 2;
        if (e0 + 3 < E) {
            int4 d4 = ((const int4*)dst)[idx];
            atomicAdd(&hist[d4.x >> RSHIFT], 1);
            atomicAdd(&hist[d4.y >> RSHIFT], 1);
            atomicAdd(&hist[d4.z >> RSHIFT], 1);
            atomicAdd(&hist[d4.w >> RSHIFT], 1);
        } else {
            for (int k = 0; k < 4; ++k)
                if (e0 + k < E) atomicAdd(&hist[dst[e0 + k] >> RSHIFT], 1);
        }
    }
    __syncthreads();
    for (int b = threadIdx.x; b < P; b += 256)
        if (hist[b] > 0) atomicAdd(&rangecnt[b], hist[b]);
}

// ---------------- rangescan: exclusive scan of rangecnt (P <= 512) + zero stats ----------------
__global__ void k_rangescan(const int* __restrict__ rangecnt, int* __restrict__ gbase,
                            int* __restrict__ gcursor, int* __restrict__ rowptr,
                            float* __restrict__ gstats, int P, int N, int E) {
    if (threadIdx.x < 128) gstats[threadIdx.x] = 0.f;
    __shared__ int s[512];
    int v = ((int)threadIdx.x < P) ? rangecnt[threadIdx.x] : 0;
    s[threadIdx.x] = v;
    __syncthreads();
    for (int off = 1; off < 512; off <<= 1) {
        int t = (threadIdx.x >= (unsigned)off) ? s[threadIdx.x - off] : 0;
        __syncthreads();
        s[threadIdx.x] += t;
        __syncthreads();
    }
    if ((int)threadIdx.x < P) {
        int ex = s[threadIdx.x] - v;
        gbase[threadIdx.x] = ex;
        gcursor[threadIdx.x] = ex;
    }
    if ((int)threadIdx.x == P - 1) gbase[P] = s[threadIdx.x];  // = E
    if (threadIdx.x == 0) rowptr[N] = E;
}

// ---------------- bin: group edges by dst-range into block-exclusive runs ----------------
// pk[pos] = (dstlocal << 20) | src   (src < 2^20, dstlocal < 256)
__global__ __launch_bounds__(256) void k_bin(const int* __restrict__ src,
                                             const int* __restrict__ dst,
                                             int* __restrict__ gcursor,
                                             int* __restrict__ pk, int P, int E) {
    __shared__ int hist[512], gofs[512], lcnt[512];
    for (int b = threadIdx.x; b < P; b += 256) { hist[b] = 0; lcnt[b] = 0; }
    __syncthreads();
    const int base4 = blockIdx.x * (EPB / 4);
    for (int i = 0; i < EPB / 4 / 256; ++i) {
        int idx = base4 + i * 256 + threadIdx.x;
        int e0 = idx << 2;
        if (e0 + 3 < E) {
            int4 d4 = ((const int4*)dst)[idx];
            atomicAdd(&hist[d4.x >> RSHIFT], 1);
            atomicAdd(&hist[d4.y >> RSHIFT], 1);
            atomicAdd(&hist[d4.z >> RSHIFT], 1);
            atomicAdd(&hist[d4.w >> RSHIFT], 1);
        } else {
            for (int k = 0; k < 4; ++k)
                if (e0 + k < E) atomicAdd(&hist[dst[e0 + k] >> RSHIFT], 1);
        }
    }
    __syncthreads();
    for (int b = threadIdx.x; b < P; b += 256)
        if (hist[b] > 0) gofs[b] = atomicAdd(&gcursor[b], hist[b]);
    __syncthreads();
    for (int i = 0; i < EPB / 4 / 256; ++i) {
        int idx = base4 + i * 256 + threadIdx.x;
        int e0 = idx << 2;
        if (e0 + 3 < E) {
            int4 d4 = ((const int4*)dst)[idx];
            int4 s4 = ((const int4*)src)[idx];
            int b;
            b = d4.x >> RSHIFT; pk[gofs[b] + atomicAdd(&lcnt[b], 1)] = ((d4.x & (RSIZE - 1)) << 20) | s4.x;
            b = d4.y >> RSHIFT; pk[gofs[b] + atomicAdd(&lcnt[b], 1)] = ((d4.y & (RSIZE - 1)) << 20) | s4.y;
            b = d4.z >> RSHIFT; pk[gofs[b] + atomicAdd(&lcnt[b], 1)] = ((d4.z & (RSIZE - 1)) << 20) | s4.z;
            b = d4.w >> RSHIFT; pk[gofs[b] + atomicAdd(&lcnt[b], 1)] = ((d4.w & (RSIZE - 1)) << 20) | s4.w;
        } else {
            for (int k = 0; k < 4; ++k) {
                if (e0 + k < E) {
                    int d = dst[e0 + k];
                    int b = d >> RSHIFT;
                    pk[gofs[b] + atomicAdd(&lcnt[b], 1)] = ((d & (RSIZE - 1)) << 20) | src[e0 + k];
                }
            }
        }
    }
}

// ---------------- sortrange: per-range LDS counting sort; derives deg/dinv/rowptr/chunkstart ----------------
__global__ __launch_bounds__(256) void k_sortrange(
        const int* __restrict__ gbase, const int* __restrict__ pk,
        int* __restrict__ ssrc, int* __restrict__ rowptr,
        int* __restrict__ chunkstart, float* __restrict__ dinv, int N) {
    __shared__ int lhist[256], ls[256], lcur[256];
    const int r = blockIdx.x;
    const int d0 = r << RSHIFT;
    const int i = d0 + threadIdx.x;
    const int ebeg = gbase[r], eend = gbase[r + 1];
    lhist[threadIdx.x] = 0;
    __syncthreads();
    for (int j = ebeg + threadIdx.x; j < eend; j += 256)
        atomicAdd(&lhist[((unsigned)pk[j]) >> 20], 1);
    __syncthreads();
    int dg = lhist[threadIdx.x];
    if (i < N) dinv[i] = rsqrtf((float)dg + 1.0f);  // +1 self-loop
    ls[threadIdx.x] = dg;
    __syncthreads();
    for (int off = 1; off < 256; off <<= 1) {
        int t = (threadIdx.x >= (unsigned)off) ? ls[threadIdx.x - off] : 0;
        __syncthreads();
        ls[threadIdx.x] += t;
        __syncthreads();
    }
    int lofs = ls[threadIdx.x] - dg;  // local exclusive
    lcur[threadIdx.x] = ebeg + lofs;  // absolute cursor
    if (i < N) {
        int rs = ebeg + lofs;
        rowptr[i] = rs;
        int rn = rs + dg;
        int c0 = (rs + 63) >> 6;
        int c1 = (rn + 63) >> 6;
        for (int c = c0; c < c1; ++c) chunkstart[c] = i;
    }
    __syncthreads();
    for (int j = ebeg + threadIdx.x; j < eend; j += 256) {
        int p = pk[j];
        ssrc[atomicAdd(&lcur[((unsigned)p) >> 20], 1)] = p & 0xFFFFF;
    }
}

// ---------------- h2 = fp16(h*dinv) AND seed out with fp32 self term ----------------
__global__ __launch_bounds__(256) void k_gemm(const float* __restrict__ x,
                                              const float* __restrict__ W,
                                              const float* __restrict__ dinv,
                                              __half* __restrict__ h2,
                                              float* __restrict__ outseed, int N) {
    __shared__ float Wl[DIM * DIM];
    for (int i = threadIdx.x; i < DIM * DIM; i += 256) Wl[i] = W[i];
    __syncthreads();
    int r = blockIdx.x * 256 + threadIdx.x;
    if (r >= N) return;
    const float4* xr4 = (const float4*)(x + (size_t)r * DIM);
    float4 acc[16];
#pragma unroll
    for (int j = 0; j < 16; ++j) acc[j] = make_float4(0.f, 0.f, 0.f, 0.f);
    for (int k0 = 0; k0 < 16; ++k0) {
        float4 xv = xr4[k0];
#pragma unroll
        for (int kk = 0; kk < 4; ++kk) {
            float xs = (&xv.x)[kk];
            const float4* wrow = (const float4*)(Wl + (k0 * 4 + kk) * DIM);
#pragma unroll
            for (int j = 0; j < 16; ++j) {
                float4 w = wrow[j];
                acc[j].x += xs * w.x;
                acc[j].y += xs * w.y;
                acc[j].z += xs * w.z;
                acc[j].w += xs * w.w;
            }
        }
    }
    float dr = dinv[r];
    float4* hr4 = (float4*)(h2 + (size_t)r * DIM);
    float4* os4 = (float4*)(outseed + (size_t)r * DIM);
    union { __half2 h[4]; float4 f4; } pack;
#pragma unroll
    for (int j = 0; j < 16; j += 2) {
        float4 v0 = make_float4(acc[j].x * dr, acc[j].y * dr, acc[j].z * dr, acc[j].w * dr);
        float4 v1 = make_float4(acc[j + 1].x * dr, acc[j + 1].y * dr, acc[j + 1].z * dr, acc[j + 1].w * dr);
        os4[j] = v0;
        os4[j + 1] = v1;
        pack.h[0] = __float22half2_rn(make_float2(v0.x, v0.y));
        pack.h[1] = __float22half2_rn(make_float2(v0.z, v0.w));
        pack.h[2] = __float22half2_rn(make_float2(v1.x, v1.y));
        pack.h[3] = __float22half2_rn(make_float2(v1.z, v1.w));
        hr4[j >> 1] = pack.f4;
    }
}

// ---------------- edge-parallel aggregate over sorted edge sources ----------------
__global__ __launch_bounds__(256) void k_edgeagg(
        const int* __restrict__ ssrc, const int* __restrict__ rowptr,
        const int* __restrict__ chunkstart, const __half* __restrict__ h2,
        float* __restrict__ agg, int N, int E) {
    const int lane = threadIdx.x & 63;
    const int wid = blockIdx.x * (blockDim.x >> 6) + (threadIdx.x >> 6);
    const int base = wid << 6;
    if (base >= E) return;
    const int nval = min(64, E - base);
    const int node0 = chunkstart[wid];
    int sv = ssrc[base + min(lane, nval - 1)];
    int nn = node0 + 1 + lane;
    if (nn > N) nn = N;
    int rp = rowptr[nn];  // lane l holds rowptr[node0+1+l]
    const __half* hb = h2 + lane;
    float acc = 0.f;
    bool uncovered = (__builtin_amdgcn_readlane(rp, 63) <= base + nval - 1);
    if (!uncovered && nval == 64) {
        int dprev = node0 + __popcll(__ballot(rp <= base));
#pragma unroll
        for (int g = 0; g < 64; g += 8) {
            int sA[8];
            float vA[8];
            int dA[8];
#pragma unroll
            for (int k = 0; k < 8; ++k) sA[k] = __builtin_amdgcn_readlane(sv, g + k);
#pragma unroll
            for (int k = 0; k < 8; ++k) vA[k] = __half2float(hb[(size_t)sA[k] * DIM]);
#pragma unroll
            for (int k = 0; k < 8; ++k) dA[k] = node0 + __popcll(__ballot(rp <= base + g + k));
#pragma unroll
            for (int k = 0; k < 8; ++k) {
                if (dA[k] != dprev) {  // wave-uniform
                    atomicAdd(&agg[(size_t)dprev * DIM + lane], acc);
                    acc = 0.f;
                    dprev = dA[k];
                }
                acc += vA[k];
            }
        }
        atomicAdd(&agg[(size_t)dprev * DIM + lane], acc);
    } else if (!uncovered) {
        int dprev = node0 + __popcll(__ballot(rp <= base));
        for (int j = 0; j < nval; ++j) {
            int sj = __builtin_amdgcn_readlane(sv, j);
            int dj = node0 + __popcll(__ballot(rp <= base + j));
            if (dj != dprev) {
                atomicAdd(&agg[(size_t)dprev * DIM + lane], acc);
                acc = 0.f;
                dprev = dj;
            }
            acc += __half2float(hb[(size_t)sj * DIM]);
        }
        atomicAdd(&agg[(size_t)dprev * DIM + lane], acc);
    } else {
        // slow path: per-edge binary search (chunk spans >64 nodes; ~never)
        int dprev = -1;
        for (int j = 0; j < nval; ++j) {
            int e = base + j;
            int lo = 0, hi = N - 1;
            while (lo < hi) {
                int mid = (lo + hi + 1) >> 1;
                if (rowptr[mid] <= e) lo = mid; else hi = mid - 1;
            }
            if (lo != dprev) {
                if (dprev >= 0) atomicAdd(&agg[(size_t)dprev * DIM + lane], acc);
                acc = 0.f;
                dprev = lo;
            }
            acc += __half2float(hb[(size_t)__builtin_amdgcn_readlane(sv, j) * DIM]);
        }
        if (dprev >= 0) atomicAdd(&agg[(size_t)dprev * DIM + lane], acc);
    }
}

// ---------------- stats: read raw out, a=relu(raw*dinv+b) on the fly, BN sums ----------------
// float4 per thread; stride multiple of 16 so feature-quad is loop-invariant
__global__ __launch_bounds__(256) void k_stats(
        const float4* __restrict__ outr, const float* __restrict__ dinv,
        const float* __restrict__ b, float* __restrict__ gsum,
        float* __restrict__ gsumsq, int total4) {
    __shared__ float4 s1[256], s2[256];
    int i = blockIdx.x * 256 + threadIdx.x;
    const int stride = gridDim.x * 256;  // 1024*256 = 262144 ≡ 0 (mod 16)
    const int f4 = i & 15;
    const float4 bv = ((const float4*)b)[f4];
    float4 ls = make_float4(0.f, 0.f, 0.f, 0.f), lq = ls;
    for (; i < total4; i += stride) {
        float dd = dinv[i >> 4];
        float4 v = outr[i];
        float ax = fmaxf(v.x * dd + bv.x, 0.f);
        float ay = fmaxf(v.y * dd + bv.y, 0.f);
        float az = fmaxf(v.z * dd + bv.z, 0.f);
        float aw = fmaxf(v.w * dd + bv.w, 0.f);
        ls.x += ax; ls.y += ay; ls.z += az; ls.w += aw;
        lq.x += ax * ax; lq.y += ay * ay; lq.z += az * az; lq.w += aw * aw;
    }
    s1[threadIdx.x] = ls;
    s2[threadIdx.x] = lq;
    __syncthreads();
    // halving reduction preserves (tid & 15) feature classes down to 16 threads
    for (int o = 128; o >= 16; o >>= 1) {
        if ((int)threadIdx.x < o) {
            float4 a = s1[threadIdx.x], c = s1[threadIdx.x + o];
            s1[threadIdx.x] = make_float4(a.x + c.x, a.y + c.y, a.z + c.z, a.w + c.w);
            float4 q = s2[threadIdx.x], r = s2[threadIdx.x + o];
            s2[threadIdx.x] = make_float4(q.x + r.x, q.y + r.y, q.z + r.z, q.w + r.w);
        }
        __syncthreads();
    }
    if (threadIdx.x < 16) {
        float4 t1 = s1[threadIdx.x], t2 = s2[threadIdx.x];
        atomicAdd(&gsum[threadIdx.x * 4 + 0], t1.x);
        atomicAdd(&gsum[threadIdx.x * 4 + 1], t1.y);
        atomicAdd(&gsum[threadIdx.x * 4 + 2], t1.z);
        atomicAdd(&gsum[threadIdx.x * 4 + 3], t1.w);
        atomicAdd(&gsumsq[threadIdx.x * 4 + 0], t2.x);
        atomicAdd(&gsumsq[threadIdx.x * 4 + 1], t2.y);
        atomicAdd(&gsumsq[threadIdx.x * 4 + 2], t2.z);
        atomicAdd(&gsumsq[threadIdx.x * 4 + 3], t2.w);
    }
}

// ---------------- bn2: recompute a=relu(raw*dinv+b), out = a*scale+shift, in-place ----------------
__global__ void k_bn2(float4* __restrict__ a, const float* __restrict__ dinv,
                      const float* __restrict__ b, const float* __restrict__ gsum,
                      const float* __restrict__ gsumsq, const float* __restrict__ gamma,
                      const float* __restrict__ beta, int N, int total4) {
    __shared__ float sc[DIM], sh[DIM];
    if (threadIdx.x < DIM) {
        float inv_n = 1.0f / (float)N;
        float mean = gsum[threadIdx.x] * inv_n;
        float var = gsumsq[threadIdx.x] * inv_n - mean * mean;
        float istd = rsqrtf(var + BN_EPS);
        float s = gamma[threadIdx.x] * istd;
        sc[threadIdx.x] = s;
        sh[threadIdx.x] = beta[threadIdx.x] - mean * s;
    }
    __syncthreads();
    int i = blockIdx.x * blockDim.x + threadIdx.x;
    const int stride = gridDim.x * blockDim.x;  // 524288 ≡ 0 (mod 16)
    const int f4 = i & 15;
    const float4 bv = ((const float4*)b)[f4];
    const float4 scv = ((const float4*)sc)[f4];
    const float4 shv = ((const float4*)sh)[f4];
    for (; i < total4; i += stride) {
        float dd = dinv[i >> 4];
        float4 v = a[i];
        v.x = fmaxf(v.x * dd + bv.x, 0.f) * scv.x + shv.x;
        v.y = fmaxf(v.y * dd + bv.y, 0.f) * scv.y + shv.y;
        v.z = fmaxf(v.z * dd + bv.z, 0.f) * scv.z + shv.z;
        v.w = fmaxf(v.w * dd + bv.w, 0.f) * scv.w + shv.w;
        a[i] = v;
    }
}

extern "C" void kernel_launch(void* const* d_in, const int* in_sizes, int n_in,
                              void* d_out, int out_size, void* d_ws, size_t ws_size,
                              hipStream_t stream) {
    const float* x     = (const float*)d_in[0];
    const int*   ei    = (const int*)d_in[1];
    const float* W     = (const float*)d_in[2];
    const float* b     = (const float*)d_in[3];
    const float* gamma = (const float*)d_in[4];
    const float* beta  = (const float*)d_in[5];
    float* out = (float*)d_out;

    const int N = in_sizes[0] / DIM;  // 100000
    const int E = in_sizes[1] / 2;    // 1000000
    const int* esrc = ei;
    const int* edst = ei + E;
    const int P = (N + RSIZE - 1) >> RSHIFT;   // 391 ranges (<= 512)
    const int nbin = (E + EPB - 1) / EPB;      // 123 bin blocks
    const int nchunks = (E + 63) / 64;         // 15625

    // workspace layout
    char* ws = (char*)d_ws;
    size_t off = 0;
    float* dinv = (float*)(ws + off);   off += (size_t)N * sizeof(float);
    off = (off + 255) & ~(size_t)255;
    int* rowptr = (int*)(ws + off);     off += (size_t)(N + 1) * sizeof(int);
    off = (off + 255) & ~(size_t)255;
    int* rangecnt = (int*)(ws + off);   off += 512 * sizeof(int);
    int* gbase = (int*)(ws + off);      off += 520 * sizeof(int);
    int* gcursor = (int*)(ws + off);    off += 512 * sizeof(int);
    float* gsum = (float*)(ws + off);   off += 64 * sizeof(float);
    float* gsumsq = (float*)(ws + off); off += 64 * sizeof(float);
    off = (off + 255) & ~(size_t)255;
    int* chunkstart = (int*)(ws + off); off += (size_t)nchunks * sizeof(int);
    off = (off + 255) & ~(size_t)255;
    int* pk = (int*)(ws + off);         off += (size_t)E * sizeof(int);
    off = (off + 255) & ~(size_t)255;
    int* ssrc = (int*)(ws + off);       off += (size_t)E * sizeof(int);
    off = (off + 255) & ~(size_t)255;
    __half* h2 = (__half*)(ws + off);   off += (size_t)N * DIM * sizeof(__half);

    hipMemsetAsync(rangecnt, 0, 512 * sizeof(int), stream);

    k_binhist<<<nbin, 256, 0, stream>>>(edst, rangecnt, P, E);
    k_rangescan<<<1, 512, 0, stream>>>(rangecnt, gbase, gcursor, rowptr, gsum, P, N, E);
    k_bin<<<nbin, 256, 0, stream>>>(esrc, edst, gcursor, pk, P, E);
    k_sortrange<<<P, 256, 0, stream>>>(gbase, pk, ssrc, rowptr, chunkstart, dinv, N);
    k_gemm<<<P, 256, 0, stream>>>(x, W, dinv, h2, out, N);
    k_edgeagg<<<(nchunks + 3) / 4, 256, 0, stream>>>(ssrc, rowptr, chunkstart, h2, out, N, E);
    k_stats<<<1024, 256, 0, stream>>>((const float4*)out, dinv, b, gsum, gsumsq, N * DIM / 4);
    k_bn2<<<2048, 256, 0, stream>>>((float4*)out, dinv, b, gsum, gsumsq, gamma, beta, N, N * DIM / 4);
}

// Round 11
// 230.750 us; speedup vs baseline: 1.4221x; 1.4221x over previous
//
#include <hip/hip_runtime.h>
#include <hip/hip_fp16.h>

#define DIM 64
#define BN_EPS 1e-5f
#define RSHIFT 8          // 256 nodes per range
#define RSIZE 256
#define EPB 8192          // edges per bin block
#define SBLK 512          // stats blocks

// ---------------- binhist: per-range edge counts via LDS histogram ----------------
__global__ __launch_bounds__(256) void k_binhist(const int* __restrict__ dst,
                                                 int* __restrict__ rangecnt,
                                                 int P, int E) {
    __shared__ int hist[512];
    for (int b = threadIdx.x; b < P; b += 256) hist[b] = 0;
    __syncthreads();
    const int base4 = blockIdx.x * (EPB / 4);
    for (int i = 0; i < EPB / 4 / 256; ++i) {
        int idx = base4 + i * 256 + threadIdx.x;
        int e0 = idx << 2;
        if (e0 + 3 < E) {
            int4 d4 = ((const int4*)dst)[idx];
            atomicAdd(&hist[d4.x >> RSHIFT], 1);
            atomicAdd(&hist[d4.y >> RSHIFT], 1);
            atomicAdd(&hist[d4.z >> RSHIFT], 1);
            atomicAdd(&hist[d4.w >> RSHIFT], 1);
        } else {
            for (int k = 0; k < 4; ++k)
                if (e0 + k < E) atomicAdd(&hist[dst[e0 + k] >> RSHIFT], 1);
        }
    }
    __syncthreads();
    for (int b = threadIdx.x; b < P; b += 256)
        if (hist[b] > 0) atomicAdd(&rangecnt[b], hist[b]);
}

// ---------------- rangescan: exclusive scan of rangecnt (P <= 512) ----------------
__global__ void k_rangescan(const int* __restrict__ rangecnt, int* __restrict__ gbase,
                            int* __restrict__ gcursor, int* __restrict__ rowptr,
                            int P, int N, int E) {
    __shared__ int s[512];
    int v = ((int)threadIdx.x < P) ? rangecnt[threadIdx.x] : 0;
    s[threadIdx.x] = v;
    __syncthreads();
    for (int off = 1; off < 512; off <<= 1) {
        int t = (threadIdx.x >= (unsigned)off) ? s[threadIdx.x - off] : 0;
        __syncthreads();
        s[threadIdx.x] += t;
        __syncthreads();
    }
    if ((int)threadIdx.x < P) {
        int ex = s[threadIdx.x] - v;
        gbase[threadIdx.x] = ex;
        gcursor[threadIdx.x] = ex;
    }
    if ((int)threadIdx.x == P - 1) gbase[P] = s[threadIdx.x];  // = E
    if (threadIdx.x == 0) rowptr[N] = E;
}

// ---------------- bin: group edges by dst-range into block-exclusive runs ----------------
// pk[pos] = (dstlocal << 20) | src   (src < 2^20, dstlocal < 256)
__global__ __launch_bounds__(256) void k_bin(const int* __restrict__ src,
                                             const int* __restrict__ dst,
                                             int* __restrict__ gcursor,
                                             int* __restrict__ pk, int P, int E) {
    __shared__ int hist[512], gofs[512], lcnt[512];
    for (int b = threadIdx.x; b < P; b += 256) { hist[b] = 0; lcnt[b] = 0; }
    __syncthreads();
    const int base4 = blockIdx.x * (EPB / 4);
    for (int i = 0; i < EPB / 4 / 256; ++i) {
        int idx = base4 + i * 256 + threadIdx.x;
        int e0 = idx << 2;
        if (e0 + 3 < E) {
            int4 d4 = ((const int4*)dst)[idx];
            atomicAdd(&hist[d4.x >> RSHIFT], 1);
            atomicAdd(&hist[d4.y >> RSHIFT], 1);
            atomicAdd(&hist[d4.z >> RSHIFT], 1);
            atomicAdd(&hist[d4.w >> RSHIFT], 1);
        } else {
            for (int k = 0; k < 4; ++k)
                if (e0 + k < E) atomicAdd(&hist[dst[e0 + k] >> RSHIFT], 1);
        }
    }
    __syncthreads();
    for (int b = threadIdx.x; b < P; b += 256)
        if (hist[b] > 0) gofs[b] = atomicAdd(&gcursor[b], hist[b]);
    __syncthreads();
    for (int i = 0; i < EPB / 4 / 256; ++i) {
        int idx = base4 + i * 256 + threadIdx.x;
        int e0 = idx << 2;
        if (e0 + 3 < E) {
            int4 d4 = ((const int4*)dst)[idx];
            int4 s4 = ((const int4*)src)[idx];
            int b;
            b = d4.x >> RSHIFT; pk[gofs[b] + atomicAdd(&lcnt[b], 1)] = ((d4.x & (RSIZE - 1)) << 20) | s4.x;
            b = d4.y >> RSHIFT; pk[gofs[b] + atomicAdd(&lcnt[b], 1)] = ((d4.y & (RSIZE - 1)) << 20) | s4.y;
            b = d4.z >> RSHIFT; pk[gofs[b] + atomicAdd(&lcnt[b], 1)] = ((d4.z & (RSIZE - 1)) << 20) | s4.z;
            b = d4.w >> RSHIFT; pk[gofs[b] + atomicAdd(&lcnt[b], 1)] = ((d4.w & (RSIZE - 1)) << 20) | s4.w;
        } else {
            for (int k = 0; k < 4; ++k) {
                if (e0 + k < E) {
                    int d = dst[e0 + k];
                    int b = d >> RSHIFT;
                    pk[gofs[b] + atomicAdd(&lcnt[b], 1)] = ((d & (RSIZE - 1)) << 20) | src[e0 + k];
                }
            }
        }
    }
}

// ---------------- sortrange: per-range LDS counting sort; derives deg/dinv/rowptr/chunkstart ----------------
__global__ __launch_bounds__(256) void k_sortrange(
        const int* __restrict__ gbase, const int* __restrict__ pk,
        int* __restrict__ ssrc, int* __restrict__ rowptr,
        int* __restrict__ chunkstart, float* __restrict__ dinv, int N) {
    __shared__ int lhist[256], ls[256], lcur[256];
    const int r = blockIdx.x;
    const int d0 = r << RSHIFT;
    const int i = d0 + threadIdx.x;
    const int ebeg = gbase[r], eend = gbase[r + 1];
    lhist[threadIdx.x] = 0;
    __syncthreads();
    for (int j = ebeg + threadIdx.x; j < eend; j += 256)
        atomicAdd(&lhist[((unsigned)pk[j]) >> 20], 1);
    __syncthreads();
    int dg = lhist[threadIdx.x];
    if (i < N) dinv[i] = rsqrtf((float)dg + 1.0f);  // +1 self-loop
    ls[threadIdx.x] = dg;
    __syncthreads();
    for (int off = 1; off < 256; off <<= 1) {
        int t = (threadIdx.x >= (unsigned)off) ? ls[threadIdx.x - off] : 0;
        __syncthreads();
        ls[threadIdx.x] += t;
        __syncthreads();
    }
    int lofs = ls[threadIdx.x] - dg;  // local exclusive
    lcur[threadIdx.x] = ebeg + lofs;  // absolute cursor
    if (i < N) {
        int rs = ebeg + lofs;
        rowptr[i] = rs;
        int rn = rs + dg;
        int c0 = (rs + 63) >> 6;
        int c1 = (rn + 63) >> 6;
        for (int c = c0; c < c1; ++c) chunkstart[c] = i;
    }
    __syncthreads();
    for (int j = ebeg + threadIdx.x; j < eend; j += 256) {
        int p = pk[j];
        ssrc[atomicAdd(&lcur[((unsigned)p) >> 20], 1)] = p & 0xFFFFF;
    }
}

// ---------------- h2 = fp16(h*dinv) AND seed out with fp32 self term ----------------
__global__ __launch_bounds__(256) void k_gemm(const float* __restrict__ x,
                                              const float* __restrict__ W,
                                              const float* __restrict__ dinv,
                                              __half* __restrict__ h2,
                                              float* __restrict__ outseed, int N) {
    __shared__ float Wl[DIM * DIM];
    for (int i = threadIdx.x; i < DIM * DIM; i += 256) Wl[i] = W[i];
    __syncthreads();
    int r = blockIdx.x * 256 + threadIdx.x;
    if (r >= N) return;
    const float4* xr4 = (const float4*)(x + (size_t)r * DIM);
    float4 acc[16];
#pragma unroll
    for (int j = 0; j < 16; ++j) acc[j] = make_float4(0.f, 0.f, 0.f, 0.f);
    for (int k0 = 0; k0 < 16; ++k0) {
        float4 xv = xr4[k0];
#pragma unroll
        for (int kk = 0; kk < 4; ++kk) {
            float xs = (&xv.x)[kk];
            const float4* wrow = (const float4*)(Wl + (k0 * 4 + kk) * DIM);
#pragma unroll
            for (int j = 0; j < 16; ++j) {
                float4 w = wrow[j];
                acc[j].x += xs * w.x;
                acc[j].y += xs * w.y;
                acc[j].z += xs * w.z;
                acc[j].w += xs * w.w;
            }
        }
    }
    float dr = dinv[r];
    float4* hr4 = (float4*)(h2 + (size_t)r * DIM);
    float4* os4 = (float4*)(outseed + (size_t)r * DIM);
    union { __half2 h[4]; float4 f4; } pack;
#pragma unroll
    for (int j = 0; j < 16; j += 2) {
        float4 v0 = make_float4(acc[j].x * dr, acc[j].y * dr, acc[j].z * dr, acc[j].w * dr);
        float4 v1 = make_float4(acc[j + 1].x * dr, acc[j + 1].y * dr, acc[j + 1].z * dr, acc[j + 1].w * dr);
        os4[j] = v0;
        os4[j + 1] = v1;
        pack.h[0] = __float22half2_rn(make_float2(v0.x, v0.y));
        pack.h[1] = __float22half2_rn(make_float2(v0.z, v0.w));
        pack.h[2] = __float22half2_rn(make_float2(v1.x, v1.y));
        pack.h[3] = __float22half2_rn(make_float2(v1.z, v1.w));
        hr4[j >> 1] = pack.f4;
    }
}

// ---------------- edge-parallel aggregate over sorted edge sources ----------------
__global__ __launch_bounds__(256) void k_edgeagg(
        const int* __restrict__ ssrc, const int* __restrict__ rowptr,
        const int* __restrict__ chunkstart, const __half* __restrict__ h2,
        float* __restrict__ agg, int N, int E) {
    const int lane = threadIdx.x & 63;
    const int wid = blockIdx.x * (blockDim.x >> 6) + (threadIdx.x >> 6);
    const int base = wid << 6;
    if (base >= E) return;
    const int nval = min(64, E - base);
    const int node0 = chunkstart[wid];
    int sv = ssrc[base + min(lane, nval - 1)];
    int nn = node0 + 1 + lane;
    if (nn > N) nn = N;
    int rp = rowptr[nn];  // lane l holds rowptr[node0+1+l]
    const __half* hb = h2 + lane;
    float acc = 0.f;
    bool uncovered = (__builtin_amdgcn_readlane(rp, 63) <= base + nval - 1);
    if (!uncovered && nval == 64) {
        int dprev = node0 + __popcll(__ballot(rp <= base));
#pragma unroll
        for (int g = 0; g < 64; g += 8) {
            int sA[8];
            float vA[8];
            int dA[8];
#pragma unroll
            for (int k = 0; k < 8; ++k) sA[k] = __builtin_amdgcn_readlane(sv, g + k);
#pragma unroll
            for (int k = 0; k < 8; ++k) vA[k] = __half2float(hb[(size_t)sA[k] * DIM]);
#pragma unroll
            for (int k = 0; k < 8; ++k) dA[k] = node0 + __popcll(__ballot(rp <= base + g + k));
#pragma unroll
            for (int k = 0; k < 8; ++k) {
                if (dA[k] != dprev) {  // wave-uniform
                    atomicAdd(&agg[(size_t)dprev * DIM + lane], acc);
                    acc = 0.f;
                    dprev = dA[k];
                }
                acc += vA[k];
            }
        }
        atomicAdd(&agg[(size_t)dprev * DIM + lane], acc);
    } else if (!uncovered) {
        int dprev = node0 + __popcll(__ballot(rp <= base));
        for (int j = 0; j < nval; ++j) {
            int sj = __builtin_amdgcn_readlane(sv, j);
            int dj = node0 + __popcll(__ballot(rp <= base + j));
            if (dj != dprev) {
                atomicAdd(&agg[(size_t)dprev * DIM + lane], acc);
                acc = 0.f;
                dprev = dj;
            }
            acc += __half2float(hb[(size_t)sj * DIM]);
        }
        atomicAdd(&agg[(size_t)dprev * DIM + lane], acc);
    } else {
        // slow path: per-edge binary search (chunk spans >64 nodes; ~never)
        int dprev = -1;
        for (int j = 0; j < nval; ++j) {
            int e = base + j;
            int lo = 0, hi = N - 1;
            while (lo < hi) {
                int mid = (lo + hi + 1) >> 1;
                if (rowptr[mid] <= e) lo = mid; else hi = mid - 1;
            }
            if (lo != dprev) {
                if (dprev >= 0) atomicAdd(&agg[(size_t)dprev * DIM + lane], acc);
                acc = 0.f;
                dprev = lo;
            }
            acc += __half2float(hb[(size_t)__builtin_amdgcn_readlane(sv, j) * DIM]);
        }
        if (dprev >= 0) atomicAdd(&agg[(size_t)dprev * DIM + lane], acc);
    }
}

// ---------------- stats: a=relu(raw*dinv+b) on the fly, per-block partials (NO atomics) ----------------
// pstats[blk*128 + f] = sum_f, pstats[blk*128 + 64 + f] = sumsq_f
__global__ __launch_bounds__(256) void k_stats(
        const float4* __restrict__ outr, const float* __restrict__ dinv,
        const float* __restrict__ b, float* __restrict__ pstats, int total4) {
    __shared__ float4 s1[256], s2[256];
    int i = blockIdx.x * 256 + threadIdx.x;
    const int stride = SBLK * 256;  // 131072 ≡ 0 (mod 16)
    const int f4 = i & 15;
    const float4 bv = ((const float4*)b)[f4];
    float4 ls = make_float4(0.f, 0.f, 0.f, 0.f), lq = ls;
    for (; i < total4; i += stride) {
        float dd = dinv[i >> 4];
        float4 v = outr[i];
        float ax = fmaxf(v.x * dd + bv.x, 0.f);
        float ay = fmaxf(v.y * dd + bv.y, 0.f);
        float az = fmaxf(v.z * dd + bv.z, 0.f);
        float aw = fmaxf(v.w * dd + bv.w, 0.f);
        ls.x += ax; ls.y += ay; ls.z += az; ls.w += aw;
        lq.x += ax * ax; lq.y += ay * ay; lq.z += az * az; lq.w += aw * aw;
    }
    s1[threadIdx.x] = ls;
    s2[threadIdx.x] = lq;
    __syncthreads();
    // halving reduction preserves (tid & 15) feature classes down to 16 threads
    for (int o = 128; o >= 16; o >>= 1) {
        if ((int)threadIdx.x < o) {
            float4 a = s1[threadIdx.x], c = s1[threadIdx.x + o];
            s1[threadIdx.x] = make_float4(a.x + c.x, a.y + c.y, a.z + c.z, a.w + c.w);
            float4 q = s2[threadIdx.x], r = s2[threadIdx.x + o];
            s2[threadIdx.x] = make_float4(q.x + r.x, q.y + r.y, q.z + r.z, q.w + r.w);
        }
        __syncthreads();
    }
    if (threadIdx.x < 16) {
        // thread t holds features t*4..t*4+3
        ((float4*)(pstats + (size_t)blockIdx.x * 128))[threadIdx.x] = s1[threadIdx.x];
        ((float4*)(pstats + (size_t)blockIdx.x * 128 + 64))[threadIdx.x] = s2[threadIdx.x];
    }
}

// ---------------- finstats: reduce partials, emit scale/shift ----------------
__global__ void k_finstats(const float* __restrict__ pstats,
                           const float* __restrict__ gamma, const float* __restrict__ beta,
                           float* __restrict__ scale, float* __restrict__ shift, int N) {
    __shared__ float ssum[256], ssq[256];
    const int f = threadIdx.x & 63;
    const int c = threadIdx.x >> 6;  // 0..3
    float s = 0.f, q = 0.f;
    for (int blk = c; blk < SBLK; blk += 4) {
        s += pstats[blk * 128 + f];
        q += pstats[blk * 128 + 64 + f];
    }
    ssum[threadIdx.x] = s;
    ssq[threadIdx.x] = q;
    __syncthreads();
    if (threadIdx.x < 64) {
        float ts = ssum[f] + ssum[f + 64] + ssum[f + 128] + ssum[f + 192];
        float tq = ssq[f] + ssq[f + 64] + ssq[f + 128] + ssq[f + 192];
        float inv_n = 1.0f / (float)N;
        float mean = ts * inv_n;
        float var = tq * inv_n - mean * mean;
        float istd = rsqrtf(var + BN_EPS);
        float sc = gamma[f] * istd;
        scale[f] = sc;
        shift[f] = beta[f] - mean * sc;
    }
}

// ---------------- bn2: recompute a=relu(raw*dinv+b), out = a*scale+shift, in-place ----------------
__global__ void k_bn2(float4* __restrict__ a, const float* __restrict__ dinv,
                      const float* __restrict__ b, const float* __restrict__ scale,
                      const float* __restrict__ shift, int total4) {
    int i = blockIdx.x * blockDim.x + threadIdx.x;
    const int stride = gridDim.x * blockDim.x;  // 524288 ≡ 0 (mod 16)
    const int f4 = i & 15;
    const float4 bv = ((const float4*)b)[f4];
    const float4 scv = ((const float4*)scale)[f4];
    const float4 shv = ((const float4*)shift)[f4];
    for (; i < total4; i += stride) {
        float dd = dinv[i >> 4];
        float4 v = a[i];
        v.x = fmaxf(v.x * dd + bv.x, 0.f) * scv.x + shv.x;
        v.y = fmaxf(v.y * dd + bv.y, 0.f) * scv.y + shv.y;
        v.z = fmaxf(v.z * dd + bv.z, 0.f) * scv.z + shv.z;
        v.w = fmaxf(v.w * dd + bv.w, 0.f) * scv.w + shv.w;
        a[i] = v;
    }
}

extern "C" void kernel_launch(void* const* d_in, const int* in_sizes, int n_in,
                              void* d_out, int out_size, void* d_ws, size_t ws_size,
                              hipStream_t stream) {
    const float* x     = (const float*)d_in[0];
    const int*   ei    = (const int*)d_in[1];
    const float* W     = (const float*)d_in[2];
    const float* b     = (const float*)d_in[3];
    const float* gamma = (const float*)d_in[4];
    const float* beta  = (const float*)d_in[5];
    float* out = (float*)d_out;

    const int N = in_sizes[0] / DIM;  // 100000
    const int E = in_sizes[1] / 2;    // 1000000
    const int* esrc = ei;
    const int* edst = ei + E;
    const int P = (N + RSIZE - 1) >> RSHIFT;   // 391 ranges (<= 512)
    const int nbin = (E + EPB - 1) / EPB;      // 123 bin blocks
    const int nchunks = (E + 63) / 64;         // 15625

    // workspace layout
    char* ws = (char*)d_ws;
    size_t off = 0;
    float* dinv = (float*)(ws + off);   off += (size_t)N * sizeof(float);
    off = (off + 255) & ~(size_t)255;
    int* rowptr = (int*)(ws + off);     off += (size_t)(N + 1) * sizeof(int);
    off = (off + 255) & ~(size_t)255;
    int* rangecnt = (int*)(ws + off);   off += 512 * sizeof(int);
    int* gbase = (int*)(ws + off);      off += 520 * sizeof(int);
    int* gcursor = (int*)(ws + off);    off += 512 * sizeof(int);
    float* scale = (float*)(ws + off);  off += 64 * sizeof(float);
    float* shift = (float*)(ws + off);  off += 64 * sizeof(float);
    off = (off + 255) & ~(size_t)255;
    float* pstats = (float*)(ws + off); off += (size_t)SBLK * 128 * sizeof(float);
    off = (off + 255) & ~(size_t)255;
    int* chunkstart = (int*)(ws + off); off += (size_t)nchunks * sizeof(int);
    off = (off + 255) & ~(size_t)255;
    int* pk = (int*)(ws + off);         off += (size_t)E * sizeof(int);
    off = (off + 255) & ~(size_t)255;
    int* ssrc = (int*)(ws + off);       off += (size_t)E * sizeof(int);
    off = (off + 255) & ~(size_t)255;
    __half* h2 = (__half*)(ws + off);   off += (size_t)N * DIM * sizeof(__half);

    hipMemsetAsync(rangecnt, 0, 512 * sizeof(int), stream);

    k_binhist<<<nbin, 256, 0, stream>>>(edst, rangecnt, P, E);
    k_rangescan<<<1, 512, 0, stream>>>(rangecnt, gbase, gcursor, rowptr, P, N, E);
    k_bin<<<nbin, 256, 0, stream>>>(esrc, edst, gcursor, pk, P, E);
    k_sortrange<<<P, 256, 0, stream>>>(gbase, pk, ssrc, rowptr, chunkstart, dinv, N);
    k_gemm<<<P, 256, 0, stream>>>(x, W, dinv, h2, out, N);
    k_edgeagg<<<(nchunks + 3) / 4, 256, 0, stream>>>(ssrc, rowptr, chunkstart, h2, out, N, E);
    k_stats<<<SBLK, 256, 0, stream>>>((const float4*)out, dinv, b, pstats, N * DIM / 4);
    k_finstats<<<1, 256, 0, stream>>>(pstats, gamma, beta, scale, shift, N);
    k_bn2<<<2048, 256, 0, stream>>>((float4*)out, dinv, b, scale, shift, N * DIM / 4);
}

// Round 12
// 216.126 us; speedup vs baseline: 1.5183x; 1.0677x over previous
//
#include <hip/hip_runtime.h>
#include <hip/hip_fp16.h>

#define DIM 64
#define BN_EPS 1e-5f
#define RSHIFT 8          // 256 nodes per range
#define RSIZE 256
#define EPB 8192          // edges per bin block
#define SBLK 512          // stats blocks

// ---------------- binhist: per-range edge counts via LDS histogram ----------------
__global__ __launch_bounds__(256) void k_binhist(const int* __restrict__ dst,
                                                 int* __restrict__ rangecnt,
                                                 int P, int E) {
    __shared__ int hist[512];
    for (int b = threadIdx.x; b < P; b += 256) hist[b] = 0;
    __syncthreads();
    const int base4 = blockIdx.x * (EPB / 4);
    for (int i = 0; i < EPB / 4 / 256; ++i) {
        int idx = base4 + i * 256 + threadIdx.x;
        int e0 = idx << 2;
        if (e0 + 3 < E) {
            int4 d4 = ((const int4*)dst)[idx];
            atomicAdd(&hist[d4.x >> RSHIFT], 1);
            atomicAdd(&hist[d4.y >> RSHIFT], 1);
            atomicAdd(&hist[d4.z >> RSHIFT], 1);
            atomicAdd(&hist[d4.w >> RSHIFT], 1);
        } else {
            for (int k = 0; k < 4; ++k)
                if (e0 + k < E) atomicAdd(&hist[dst[e0 + k] >> RSHIFT], 1);
        }
    }
    __syncthreads();
    for (int b = threadIdx.x; b < P; b += 256)
        if (hist[b] > 0) atomicAdd(&rangecnt[b], hist[b]);
}

// ---------------- rangescan: exclusive scan of rangecnt (P <= 512) ----------------
__global__ void k_rangescan(const int* __restrict__ rangecnt, int* __restrict__ gbase,
                            int* __restrict__ gcursor, int* __restrict__ rowptr,
                            int P, int N, int E) {
    __shared__ int s[512];
    int v = ((int)threadIdx.x < P) ? rangecnt[threadIdx.x] : 0;
    s[threadIdx.x] = v;
    __syncthreads();
    for (int off = 1; off < 512; off <<= 1) {
        int t = (threadIdx.x >= (unsigned)off) ? s[threadIdx.x - off] : 0;
        __syncthreads();
        s[threadIdx.x] += t;
        __syncthreads();
    }
    if ((int)threadIdx.x < P) {
        int ex = s[threadIdx.x] - v;
        gbase[threadIdx.x] = ex;
        gcursor[threadIdx.x] = ex;
    }
    if ((int)threadIdx.x == P - 1) gbase[P] = s[threadIdx.x];  // = E
    if (threadIdx.x == 0) rowptr[N] = E;
}

// ---------------- bin: group edges by dst-range into block-exclusive runs ----------------
// pk[pos] = (dstlocal << 20) | src   (src < 2^20, dstlocal < 256)
__global__ __launch_bounds__(256) void k_bin(const int* __restrict__ src,
                                             const int* __restrict__ dst,
                                             int* __restrict__ gcursor,
                                             int* __restrict__ pk, int P, int E) {
    __shared__ int hist[512], gofs[512], lcnt[512];
    for (int b = threadIdx.x; b < P; b += 256) { hist[b] = 0; lcnt[b] = 0; }
    __syncthreads();
    const int base4 = blockIdx.x * (EPB / 4);
    for (int i = 0; i < EPB / 4 / 256; ++i) {
        int idx = base4 + i * 256 + threadIdx.x;
        int e0 = idx << 2;
        if (e0 + 3 < E) {
            int4 d4 = ((const int4*)dst)[idx];
            atomicAdd(&hist[d4.x >> RSHIFT], 1);
            atomicAdd(&hist[d4.y >> RSHIFT], 1);
            atomicAdd(&hist[d4.z >> RSHIFT], 1);
            atomicAdd(&hist[d4.w >> RSHIFT], 1);
        } else {
            for (int k = 0; k < 4; ++k)
                if (e0 + k < E) atomicAdd(&hist[dst[e0 + k] >> RSHIFT], 1);
        }
    }
    __syncthreads();
    for (int b = threadIdx.x; b < P; b += 256)
        if (hist[b] > 0) gofs[b] = atomicAdd(&gcursor[b], hist[b]);
    __syncthreads();
    for (int i = 0; i < EPB / 4 / 256; ++i) {
        int idx = base4 + i * 256 + threadIdx.x;
        int e0 = idx << 2;
        if (e0 + 3 < E) {
            int4 d4 = ((const int4*)dst)[idx];
            int4 s4 = ((const int4*)src)[idx];
            int b;
            b = d4.x >> RSHIFT; pk[gofs[b] + atomicAdd(&lcnt[b], 1)] = ((d4.x & (RSIZE - 1)) << 20) | s4.x;
            b = d4.y >> RSHIFT; pk[gofs[b] + atomicAdd(&lcnt[b], 1)] = ((d4.y & (RSIZE - 1)) << 20) | s4.y;
            b = d4.z >> RSHIFT; pk[gofs[b] + atomicAdd(&lcnt[b], 1)] = ((d4.z & (RSIZE - 1)) << 20) | s4.z;
            b = d4.w >> RSHIFT; pk[gofs[b] + atomicAdd(&lcnt[b], 1)] = ((d4.w & (RSIZE - 1)) << 20) | s4.w;
        } else {
            for (int k = 0; k < 4; ++k) {
                if (e0 + k < E) {
                    int d = dst[e0 + k];
                    int b = d >> RSHIFT;
                    pk[gofs[b] + atomicAdd(&lcnt[b], 1)] = ((d & (RSIZE - 1)) << 20) | src[e0 + k];
                }
            }
        }
    }
}

// ---------------- sortrange: per-range LDS counting sort; derives deg/dinv/rowptr/chunkstart ----------------
__global__ __launch_bounds__(256) void k_sortrange(
        const int* __restrict__ gbase, const int* __restrict__ pk,
        int* __restrict__ ssrc, int* __restrict__ rowptr,
        int* __restrict__ chunkstart, float* __restrict__ dinv, int N) {
    __shared__ int lhist[256], ls[256], lcur[256];
    const int r = blockIdx.x;
    const int d0 = r << RSHIFT;
    const int i = d0 + threadIdx.x;
    const int ebeg = gbase[r], eend = gbase[r + 1];
    lhist[threadIdx.x] = 0;
    __syncthreads();
    for (int j = ebeg + threadIdx.x; j < eend; j += 256)
        atomicAdd(&lhist[((unsigned)pk[j]) >> 20], 1);
    __syncthreads();
    int dg = lhist[threadIdx.x];
    if (i < N) dinv[i] = rsqrtf((float)dg + 1.0f);  // +1 self-loop
    ls[threadIdx.x] = dg;
    __syncthreads();
    for (int off = 1; off < 256; off <<= 1) {
        int t = (threadIdx.x >= (unsigned)off) ? ls[threadIdx.x - off] : 0;
        __syncthreads();
        ls[threadIdx.x] += t;
        __syncthreads();
    }
    int lofs = ls[threadIdx.x] - dg;  // local exclusive
    lcur[threadIdx.x] = ebeg + lofs;  // absolute cursor
    if (i < N) {
        int rs = ebeg + lofs;
        rowptr[i] = rs;
        int rn = rs + dg;
        int c0 = (rs + 63) >> 6;
        int c1 = (rn + 63) >> 6;
        for (int c = c0; c < c1; ++c) chunkstart[c] = i;
    }
    __syncthreads();
    for (int j = ebeg + threadIdx.x; j < eend; j += 256) {
        int p = pk[j];
        ssrc[atomicAdd(&lcur[((unsigned)p) >> 20], 1)] = p & 0xFFFFF;
    }
}

// ---------------- gemm: 4 threads/row, each computes 16 output features ----------------
// h2 = fp16(h*dinv) AND seed out with fp32 self term. Grid = ceil(4N/256).
__global__ __launch_bounds__(256) void k_gemm(const float* __restrict__ x,
                                              const float* __restrict__ W,
                                              const float* __restrict__ dinv,
                                              __half* __restrict__ h2,
                                              float* __restrict__ outseed, int N) {
    __shared__ float Wl[DIM * DIM];
    for (int i = threadIdx.x; i < DIM * DIM; i += 256) Wl[i] = W[i];
    __syncthreads();
    int t = blockIdx.x * 256 + threadIdx.x;
    int r = t >> 2;       // row
    int q = t & 3;        // output-feature quarter (features q*16 .. q*16+15)
    if (r >= N) return;
    const float4* xr4 = (const float4*)(x + (size_t)r * DIM);
    float4 acc[4];
#pragma unroll
    for (int j = 0; j < 4; ++j) acc[j] = make_float4(0.f, 0.f, 0.f, 0.f);
    for (int k0 = 0; k0 < 16; ++k0) {
        float4 xv = xr4[k0];  // lanes q=0..3 of a row: same address (broadcast)
#pragma unroll
        for (int kk = 0; kk < 4; ++kk) {
            float xs = (&xv.x)[kk];
            const float4* wrow = (const float4*)(Wl + (k0 * 4 + kk) * DIM) + (q << 2);
#pragma unroll
            for (int j = 0; j < 4; ++j) {
                float4 w = wrow[j];
                acc[j].x += xs * w.x;
                acc[j].y += xs * w.y;
                acc[j].z += xs * w.z;
                acc[j].w += xs * w.w;
            }
        }
    }
    float dr = dinv[r];
    float4* os4 = (float4*)(outseed + (size_t)r * DIM) + (q << 2);
    float4* hr4 = (float4*)(h2 + (size_t)r * DIM) + (q << 1);
    union { __half2 h[4]; float4 f4; } pack;
#pragma unroll
    for (int j = 0; j < 4; j += 2) {
        float4 v0 = make_float4(acc[j].x * dr, acc[j].y * dr, acc[j].z * dr, acc[j].w * dr);
        float4 v1 = make_float4(acc[j + 1].x * dr, acc[j + 1].y * dr, acc[j + 1].z * dr, acc[j + 1].w * dr);
        os4[j] = v0;
        os4[j + 1] = v1;
        pack.h[0] = __float22half2_rn(make_float2(v0.x, v0.y));
        pack.h[1] = __float22half2_rn(make_float2(v0.z, v0.w));
        pack.h[2] = __float22half2_rn(make_float2(v1.x, v1.y));
        pack.h[3] = __float22half2_rn(make_float2(v1.z, v1.w));
        hr4[j >> 1] = pack.f4;
    }
}

// ---------------- edge-parallel aggregate over sorted edge sources ----------------
__global__ __launch_bounds__(256) void k_edgeagg(
        const int* __restrict__ ssrc, const int* __restrict__ rowptr,
        const int* __restrict__ chunkstart, const __half* __restrict__ h2,
        float* __restrict__ agg, int N, int E) {
    const int lane = threadIdx.x & 63;
    const int wid = blockIdx.x * (blockDim.x >> 6) + (threadIdx.x >> 6);
    const int base = wid << 6;
    if (base >= E) return;
    const int nval = min(64, E - base);
    const int node0 = chunkstart[wid];
    int sv = ssrc[base + min(lane, nval - 1)];
    int nn = node0 + 1 + lane;
    if (nn > N) nn = N;
    int rp = rowptr[nn];  // lane l holds rowptr[node0+1+l]
    const __half* hb = h2 + lane;
    float acc = 0.f;
    bool uncovered = (__builtin_amdgcn_readlane(rp, 63) <= base + nval - 1);
    if (!uncovered && nval == 64) {
        int dprev = node0 + __popcll(__ballot(rp <= base));
#pragma unroll
        for (int g = 0; g < 64; g += 8) {
            int sA[8];
            float vA[8];
            int dA[8];
#pragma unroll
            for (int k = 0; k < 8; ++k) sA[k] = __builtin_amdgcn_readlane(sv, g + k);
#pragma unroll
            for (int k = 0; k < 8; ++k) vA[k] = __half2float(hb[(size_t)sA[k] * DIM]);
#pragma unroll
            for (int k = 0; k < 8; ++k) dA[k] = node0 + __popcll(__ballot(rp <= base + g + k));
#pragma unroll
            for (int k = 0; k < 8; ++k) {
                if (dA[k] != dprev) {  // wave-uniform
                    atomicAdd(&agg[(size_t)dprev * DIM + lane], acc);
                    acc = 0.f;
                    dprev = dA[k];
                }
                acc += vA[k];
            }
        }
        atomicAdd(&agg[(size_t)dprev * DIM + lane], acc);
    } else if (!uncovered) {
        int dprev = node0 + __popcll(__ballot(rp <= base));
        for (int j = 0; j < nval; ++j) {
            int sj = __builtin_amdgcn_readlane(sv, j);
            int dj = node0 + __popcll(__ballot(rp <= base + j));
            if (dj != dprev) {
                atomicAdd(&agg[(size_t)dprev * DIM + lane], acc);
                acc = 0.f;
                dprev = dj;
            }
            acc += __half2float(hb[(size_t)sj * DIM]);
        }
        atomicAdd(&agg[(size_t)dprev * DIM + lane], acc);
    } else {
        // slow path: per-edge binary search (chunk spans >64 nodes; ~never)
        int dprev = -1;
        for (int j = 0; j < nval; ++j) {
            int e = base + j;
            int lo = 0, hi = N - 1;
            while (lo < hi) {
                int mid = (lo + hi + 1) >> 1;
                if (rowptr[mid] <= e) lo = mid; else hi = mid - 1;
            }
            if (lo != dprev) {
                if (dprev >= 0) atomicAdd(&agg[(size_t)dprev * DIM + lane], acc);
                acc = 0.f;
                dprev = lo;
            }
            acc += __half2float(hb[(size_t)__builtin_amdgcn_readlane(sv, j) * DIM]);
        }
        if (dprev >= 0) atomicAdd(&agg[(size_t)dprev * DIM + lane], acc);
    }
}

// ---------------- stats: a=relu(raw*dinv+b) on the fly, per-block partials (NO atomics) ----------------
// pstats[blk*128 + f] = sum_f, pstats[blk*128 + 64 + f] = sumsq_f
__global__ __launch_bounds__(256) void k_stats(
        const float4* __restrict__ outr, const float* __restrict__ dinv,
        const float* __restrict__ b, float* __restrict__ pstats, int total4) {
    __shared__ float4 s1[256], s2[256];
    int i = blockIdx.x * 256 + threadIdx.x;
    const int stride = SBLK * 256;  // 131072 ≡ 0 (mod 16)
    const int f4 = i & 15;
    const float4 bv = ((const float4*)b)[f4];
    float4 ls = make_float4(0.f, 0.f, 0.f, 0.f), lq = ls;
    for (; i < total4; i += stride) {
        float dd = dinv[i >> 4];
        float4 v = outr[i];
        float ax = fmaxf(v.x * dd + bv.x, 0.f);
        float ay = fmaxf(v.y * dd + bv.y, 0.f);
        float az = fmaxf(v.z * dd + bv.z, 0.f);
        float aw = fmaxf(v.w * dd + bv.w, 0.f);
        ls.x += ax; ls.y += ay; ls.z += az; ls.w += aw;
        lq.x += ax * ax; lq.y += ay * ay; lq.z += az * az; lq.w += aw * aw;
    }
    s1[threadIdx.x] = ls;
    s2[threadIdx.x] = lq;
    __syncthreads();
    // halving reduction preserves (tid & 15) feature classes down to 16 threads
    for (int o = 128; o >= 16; o >>= 1) {
        if ((int)threadIdx.x < o) {
            float4 a = s1[threadIdx.x], c = s1[threadIdx.x + o];
            s1[threadIdx.x] = make_float4(a.x + c.x, a.y + c.y, a.z + c.z, a.w + c.w);
            float4 q = s2[threadIdx.x], r = s2[threadIdx.x + o];
            s2[threadIdx.x] = make_float4(q.x + r.x, q.y + r.y, q.z + r.z, q.w + r.w);
        }
        __syncthreads();
    }
    if (threadIdx.x < 16) {
        ((float4*)(pstats + (size_t)blockIdx.x * 128))[threadIdx.x] = s1[threadIdx.x];
        ((float4*)(pstats + (size_t)blockIdx.x * 128 + 64))[threadIdx.x] = s2[threadIdx.x];
    }
}

// ---------------- finstats: reduce partials, emit scale/shift ----------------
__global__ void k_finstats(const float* __restrict__ pstats,
                           const float* __restrict__ gamma, const float* __restrict__ beta,
                           float* __restrict__ scale, float* __restrict__ shift, int N) {
    __shared__ float ssum[256], ssq[256];
    const int f = threadIdx.x & 63;
    const int c = threadIdx.x >> 6;  // 0..3
    float s = 0.f, q = 0.f;
    for (int blk = c; blk < SBLK; blk += 4) {
        s += pstats[blk * 128 + f];
        q += pstats[blk * 128 + 64 + f];
    }
    ssum[threadIdx.x] = s;
    ssq[threadIdx.x] = q;
    __syncthreads();
    if (threadIdx.x < 64) {
        float ts = ssum[f] + ssum[f + 64] + ssum[f + 128] + ssum[f + 192];
        float tq = ssq[f] + ssq[f + 64] + ssq[f + 128] + ssq[f + 192];
        float inv_n = 1.0f / (float)N;
        float mean = ts * inv_n;
        float var = tq * inv_n - mean * mean;
        float istd = rsqrtf(var + BN_EPS);
        float sc = gamma[f] * istd;
        scale[f] = sc;
        shift[f] = beta[f] - mean * sc;
    }
}

// ---------------- bn2: recompute a=relu(raw*dinv+b), out = a*scale+shift, in-place ----------------
__global__ void k_bn2(float4* __restrict__ a, const float* __restrict__ dinv,
                      const float* __restrict__ b, const float* __restrict__ scale,
                      const float* __restrict__ shift, int total4) {
    int i = blockIdx.x * blockDim.x + threadIdx.x;
    const int stride = gridDim.x * blockDim.x;  // 524288 ≡ 0 (mod 16)
    const int f4 = i & 15;
    const float4 bv = ((const float4*)b)[f4];
    const float4 scv = ((const float4*)scale)[f4];
    const float4 shv = ((const float4*)shift)[f4];
    for (; i < total4; i += stride) {
        float dd = dinv[i >> 4];
        float4 v = a[i];
        v.x = fmaxf(v.x * dd + bv.x, 0.f) * scv.x + shv.x;
        v.y = fmaxf(v.y * dd + bv.y, 0.f) * scv.y + shv.y;
        v.z = fmaxf(v.z * dd + bv.z, 0.f) * scv.z + shv.z;
        v.w = fmaxf(v.w * dd + bv.w, 0.f) * scv.w + shv.w;
        a[i] = v;
    }
}

extern "C" void kernel_launch(void* const* d_in, const int* in_sizes, int n_in,
                              void* d_out, int out_size, void* d_ws, size_t ws_size,
                              hipStream_t stream) {
    const float* x     = (const float*)d_in[0];
    const int*   ei    = (const int*)d_in[1];
    const float* W     = (const float*)d_in[2];
    const float* b     = (const float*)d_in[3];
    const float* gamma = (const float*)d_in[4];
    const float* beta  = (const float*)d_in[5];
    float* out = (float*)d_out;

    const int N = in_sizes[0] / DIM;  // 100000
    const int E = in_sizes[1] / 2;    // 1000000
    const int* esrc = ei;
    const int* edst = ei + E;
    const int P = (N + RSIZE - 1) >> RSHIFT;   // 391 ranges (<= 512)
    const int nbin = (E + EPB - 1) / EPB;      // 123 bin blocks
    const int nchunks = (E + 63) / 64;         // 15625

    // workspace layout
    char* ws = (char*)d_ws;
    size_t off = 0;
    float* dinv = (float*)(ws + off);   off += (size_t)N * sizeof(float);
    off = (off + 255) & ~(size_t)255;
    int* rowptr = (int*)(ws + off);     off += (size_t)(N + 1) * sizeof(int);
    off = (off + 255) & ~(size_t)255;
    int* rangecnt = (int*)(ws + off);   off += 512 * sizeof(int);
    int* gbase = (int*)(ws + off);      off += 520 * sizeof(int);
    int* gcursor = (int*)(ws + off);    off += 512 * sizeof(int);
    float* scale = (float*)(ws + off);  off += 64 * sizeof(float);
    float* shift = (float*)(ws + off);  off += 64 * sizeof(float);
    off = (off + 255) & ~(size_t)255;
    float* pstats = (float*)(ws + off); off += (size_t)SBLK * 128 * sizeof(float);
    off = (off + 255) & ~(size_t)255;
    int* chunkstart = (int*)(ws + off); off += (size_t)nchunks * sizeof(int);
    off = (off + 255) & ~(size_t)255;
    int* pk = (int*)(ws + off);         off += (size_t)E * sizeof(int);
    off = (off + 255) & ~(size_t)255;
    int* ssrc = (int*)(ws + off);       off += (size_t)E * sizeof(int);
    off = (off + 255) & ~(size_t)255;
    __half* h2 = (__half*)(ws + off);   off += (size_t)N * DIM * sizeof(__half);

    hipMemsetAsync(rangecnt, 0, 512 * sizeof(int), stream);

    k_binhist<<<nbin, 256, 0, stream>>>(edst, rangecnt, P, E);
    k_rangescan<<<1, 512, 0, stream>>>(rangecnt, gbase, gcursor, rowptr, P, N, E);
    k_bin<<<nbin, 256, 0, stream>>>(esrc, edst, gcursor, pk, P, E);
    k_sortrange<<<P, 256, 0, stream>>>(gbase, pk, ssrc, rowptr, chunkstart, dinv, N);
    k_gemm<<<(4 * N + 255) / 256, 256, 0, stream>>>(x, W, dinv, h2, out, N);
    k_edgeagg<<<(nchunks + 3) / 4, 256, 0, stream>>>(ssrc, rowptr, chunkstart, h2, out, N, E);
    k_stats<<<SBLK, 256, 0, stream>>>((const float4*)out, dinv, b, pstats, N * DIM / 4);
    k_finstats<<<1, 256, 0, stream>>>(pstats, gamma, beta, scale, shift, N);
    k_bn2<<<2048, 256, 0, stream>>>((float4*)out, dinv, b, scale, shift, N * DIM / 4);
}